// Round 1
// baseline (345.529 us; speedup 1.0000x reference)
//
#include <hip/hip_runtime.h>

// Aggregation: out[n, g*32+wc, h, w] =
//   sum_{kh,kw} x[n, g*32+wc, reflect(h+kh-1), reflect(w+kw-1)] * weight[n, wc, kh*3+kw, h, w]
// N=8, C=256, WC=32, G=8, H=W=128, K=3, PAD=1 (reflect, no edge repeat).
// Memory-bound: floor ~420 MB -> ~67 us @ 6.3 TB/s.

#define NN 8
#define CC 256
#define WCC 32
#define GG 8
#define HH 128
#define WW 128

__global__ __launch_bounds__(256) void agg_kernel(const float* __restrict__ x,
                                                  const float* __restrict__ wgt,
                                                  float* __restrict__ out) {
    // tid -> (n, wc, h, w4); consecutive threads = consecutive w4 (coalesced)
    const int tid = blockIdx.x * blockDim.x + threadIdx.x;
    const int w4 = tid & 31;            // 32 float4 blocks per row
    const int h  = (tid >> 5) & 127;
    const int wc = (tid >> 12) & 31;
    const int n  = tid >> 17;
    const int w0 = w4 * 4;

    // Load the 9 weight taps for this (n, wc, h, w0..w0+3) once; reused by all 8 groups.
    // weight layout: (((n*WC + wc)*9 + k)*H + h)*W + w
    const float* wbase = wgt + (((size_t)(n * WCC + wc) * 9) * HH + h) * (size_t)WW + w0;
    float4 wk[9];
    #pragma unroll
    for (int k = 0; k < 9; ++k)
        wk[k] = *(const float4*)(wbase + (size_t)k * (HH * WW));

    // Reflect h indices for the 3 vertical taps (PAD=1 reflect: -1 -> 1, H -> H-2)
    int hh[3];
    #pragma unroll
    for (int kh = 0; kh < 3; ++kh) {
        int t = h + kh - 1;
        hh[kh] = (t < 0) ? 1 : ((t >= HH) ? (HH - 2) : t);
    }

    const size_t chanStride = (size_t)HH * WW;                  // 16384
    const float* xbase = x   + ((size_t)n * CC + wc) * chanStride;
    float*       obase = out + ((size_t)n * CC + wc) * chanStride + (size_t)h * WW + w0;

    for (int g = 0; g < GG; ++g) {
        const float* xchan = xbase + (size_t)g * WCC * chanStride;
        float a0 = 0.f, a1 = 0.f, a2 = 0.f, a3 = 0.f;
        #pragma unroll
        for (int kh = 0; kh < 3; ++kh) {
            const float* xrow = xchan + (size_t)hh[kh] * WW;
            const float4 xv = *(const float4*)(xrow + w0);
            // horizontal halo with reflect: col -1 -> 1, col 128 -> 126
            const float xl = (w0 == 0)       ? xrow[1]      : xrow[w0 - 1];
            const float xr = (w0 == WW - 4)  ? xrow[WW - 2] : xrow[w0 + 4];
            const float4 wl = wk[kh * 3 + 0];
            const float4 wm = wk[kh * 3 + 1];
            const float4 wr = wk[kh * 3 + 2];
            a0 += wl.x * xl   + wm.x * xv.x + wr.x * xv.y;
            a1 += wl.y * xv.x + wm.y * xv.y + wr.y * xv.z;
            a2 += wl.z * xv.y + wm.z * xv.z + wr.z * xv.w;
            a3 += wl.w * xv.z + wm.w * xv.w + wr.w * xr;
        }
        *(float4*)(obase + (size_t)g * WCC * chanStride) = make_float4(a0, a1, a2, a3);
    }
}

extern "C" void kernel_launch(void* const* d_in, const int* in_sizes, int n_in,
                              void* d_out, int out_size, void* d_ws, size_t ws_size,
                              hipStream_t stream) {
    const float* x   = (const float*)d_in[0];
    const float* wgt = (const float*)d_in[1];
    float* out = (float*)d_out;

    // total threads: N * WC * H * (W/4) = 8*32*128*32 = 1,048,576 -> 4096 blocks
    const int total = NN * WCC * HH * (WW / 4);
    agg_kernel<<<total / 256, 256, 0, stream>>>(x, wgt, out);
}